// Round 1
// baseline (293.584 us; speedup 1.0000x reference)
//
#include <hip/hip_runtime.h>
#include <cstdint>
#include <cstddef>

#define LDIM 6
#define BDIM 4
#define QDIM 900
#define CDIM 256
#define NDIM (LDIM*QDIM)   /* 5400 */
#define NN   5408          /* padded per-image stride */
#define TT   85            /* ceil(5400/64) */
#define NTRI (TT*(TT+1)/2) /* 3655 lower-tri 64x64 tiles */

__device__ __forceinline__ int sig_off(int b, int n) {
    int l = n / QDIM, q = n - l * QDIM;
    return ((l * BDIM + b) * QDIM + q) * CDIM;
}
__device__ __forceinline__ int logit_off(int b, int n) {
    int l = n / QDIM, q = n - l * QDIM;
    return (l * BDIM + b) * QDIM + q;
}

__device__ __forceinline__ int uf_load(const int* p, int i) {
    return __hip_atomic_load(&p[i], __ATOMIC_RELAXED, __HIP_MEMORY_SCOPE_AGENT);
}
__device__ int uf_find(int* p, int x) {
    int r = x;
    int pr = uf_load(p, r);
    while (pr != r) { r = pr; pr = uf_load(p, r); }
    return r;
}
__device__ void uf_union(int* p, int a, int b) {
    int ra = uf_find(p, a), rb = uf_find(p, b);
    while (ra != rb) {
        int hi = ra > rb ? ra : rb;
        int lo = ra ^ rb ^ hi;
        int old = atomicCAS(&p[hi], hi, lo);
        if (old == hi) return;
        ra = uf_find(p, old);
        rb = uf_find(p, lo);
    }
}

// K1: scores, sel flags, parent init, compBest init, per-image selCount + argmax key
__global__ void k_init(const float* __restrict__ logits, float* __restrict__ scores,
                       int* __restrict__ sel, int* __restrict__ parent,
                       int* __restrict__ compBest, int* __restrict__ selCount,
                       unsigned long long* __restrict__ argKey) {
    int b = blockIdx.y;
    int n = blockIdx.x * blockDim.x + threadIdx.x;
    unsigned long long key = 0ULL;
    int s = 0;
    if (n < NDIM) {
        float x = logits[logit_off(b, n)];
        float sc = 1.0f / (1.0f + expf(-x));
        scores[b * NN + n] = sc;
        s = (sc >= 0.5f) ? 1 : 0;
        sel[b * NN + n] = s;
        parent[b * NN + n] = n;
        compBest[b * NN + n] = 0x7fffffff;
        key = ((unsigned long long)__float_as_uint(sc) << 32) | (unsigned int)(~n);
    }
    unsigned long long bal = __ballot(s != 0);
    int cnt = __popcll(bal);
    for (int off = 32; off; off >>= 1) {
        unsigned long long o = __shfl_down(key, off);
        if (o > key) key = o;
    }
    if ((threadIdx.x & 63) == 0) {
        if (cnt) atomicAdd(&selCount[b], cnt);
        atomicMax(&argKey[b], key);
    }
}

// K2: inverse norms, one wave per node
__global__ void k_norm(const float* __restrict__ sig, float* __restrict__ ninv) {
    int b = blockIdx.y;
    int wave = (blockIdx.x * blockDim.x + threadIdx.x) >> 6;
    int lane = threadIdx.x & 63;
    if (wave >= NDIM) return;
    const float4 v = *(const float4*)(sig + sig_off(b, wave) + lane * 4);
    float s = v.x * v.x + v.y * v.y + v.z * v.z + v.w * v.w;
    for (int off = 32; off; off >>= 1) s += __shfl_down(s, off);
    if (lane == 0) ninv[b * NN + wave] = rsqrtf(s + 1e-12f);
}

// K3: fallback argmax select if nothing passed the threshold
__global__ void k_resolve(int* __restrict__ sel, int* __restrict__ selCount,
                          const unsigned long long* __restrict__ argKey) {
    int b = threadIdx.x;
    if (b >= BDIM) return;
    if (selCount[b] == 0) {
        int n = (int)(~(unsigned int)(argKey[b] & 0xffffffffULL));
        sel[b * NN + n] = 1;
        selCount[b] = 1;
    }
}

// K4: ordered compaction of selected node indices (one 1024-thread block per image)
__global__ void k_compact(const int* __restrict__ sel, int* __restrict__ selIdx,
                          int* __restrict__ Mcnt) {
    int b = blockIdx.x, t = threadIdx.x;
    __shared__ int sh[1024];
    __shared__ int sbase;
    if (t == 0) sbase = 0;
    __syncthreads();
    for (int base = 0; base < NDIM; base += 1024) {
        int n = base + t;
        int f = (n < NDIM) ? sel[b * NN + n] : 0;
        sh[t] = f;
        __syncthreads();
        for (int off = 1; off < 1024; off <<= 1) {
            int v = (t >= off) ? sh[t - off] : 0;
            __syncthreads();
            sh[t] += v;
            __syncthreads();
        }
        if (f) selIdx[b * NN + sbase + sh[t] - 1] = n;
        __syncthreads();
        if (t == 0) sbase += sh[1023];
        __syncthreads();
    }
    if (t == 0) Mcnt[b] = sbase;
}

// K5: 64x64 tiled pairwise sims over selected nodes (lower triangle), union on sim>=0.8
__global__ __launch_bounds__(256) void k_sim(const float* __restrict__ sig,
                                             const float* __restrict__ ninv,
                                             const int* __restrict__ selIdx,
                                             const int* __restrict__ Mcnt,
                                             int* __restrict__ parent) {
    int b = blockIdx.y;
    int M = Mcnt[b];
    int t = blockIdx.x;
    int ti = (int)((sqrtf(8.0f * (float)t + 1.0f) - 1.0f) * 0.5f);
    while ((ti + 1) * (ti + 2) / 2 <= t) ti++;
    while (ti * (ti + 1) / 2 > t) ti--;
    int tj = t - ti * (ti + 1) / 2;
    if (ti * 64 >= M) return;

    __shared__ float As[64][17], Bs[64][17];
    __shared__ int idxA[64], idxB[64], offA[64], offB[64];
    __shared__ float nvA[64], nvB[64];

    int tid = threadIdx.x;
    if (tid < 64) {
        int gi = ti * 64 + tid;
        int g = min(gi, M - 1);
        int node = selIdx[b * NN + g];
        idxA[tid] = node;
        offA[tid] = sig_off(b, node);
        nvA[tid] = ninv[b * NN + node];
    } else if (tid < 128) {
        int lid = tid - 64;
        int gj = tj * 64 + lid;
        int g = min(gj, M - 1);
        int node = selIdx[b * NN + g];
        idxB[lid] = node;
        offB[lid] = sig_off(b, node);
        nvB[lid] = ninv[b * NN + node];
    }
    __syncthreads();

    float acc[4][4] = {};
    int r = tid >> 2;
    int c4 = (tid & 3) * 4;
    int i0 = (tid >> 4) * 4;
    int j0 = (tid & 15) * 4;

    for (int k0 = 0; k0 < CDIM; k0 += 16) {
        float4 a = *(const float4*)(sig + offA[r] + k0 + c4);
        float4 bb = *(const float4*)(sig + offB[r] + k0 + c4);
        As[r][c4 + 0] = a.x; As[r][c4 + 1] = a.y; As[r][c4 + 2] = a.z; As[r][c4 + 3] = a.w;
        Bs[r][c4 + 0] = bb.x; Bs[r][c4 + 1] = bb.y; Bs[r][c4 + 2] = bb.z; Bs[r][c4 + 3] = bb.w;
        __syncthreads();
#pragma unroll
        for (int kk = 0; kk < 16; kk++) {
            float av[4], bv[4];
#pragma unroll
            for (int x = 0; x < 4; x++) { av[x] = As[i0 + x][kk]; bv[x] = Bs[j0 + x][kk]; }
#pragma unroll
            for (int x = 0; x < 4; x++)
#pragma unroll
                for (int y = 0; y < 4; y++) acc[x][y] += av[x] * bv[y];
        }
        __syncthreads();
    }

#pragma unroll
    for (int x = 0; x < 4; x++) {
#pragma unroll
        for (int y = 0; y < 4; y++) {
            int gi = ti * 64 + i0 + x;
            int gj = tj * 64 + j0 + y;
            if (gi < M && gj < M && gi > gj) {
                float sim = acc[x][y] * nvA[i0 + x] * nvB[j0 + y];
                if (sim >= 0.8f) uf_union(parent + b * NN, idxA[i0 + x], idxB[j0 + y]);
            }
        }
    }
}

// K6: flatten labels + per-component max score (positive floats as uint -> order-preserving)
__global__ void k_flatten(const int* __restrict__ parent, int* __restrict__ labels,
                          const int* __restrict__ sel, const float* __restrict__ scores,
                          unsigned int* __restrict__ compMaxU) {
    int b = blockIdx.y;
    int n = blockIdx.x * blockDim.x + threadIdx.x;
    if (n >= NDIM) return;
    int r = n, pr = parent[b * NN + r];
    while (pr != r) { r = pr; pr = parent[b * NN + r]; }
    labels[b * NN + n] = r;
    if (sel[b * NN + n])
        atomicMax(&compMaxU[b * NN + r], __float_as_uint(scores[b * NN + n]));
}

// K7: per-component smallest index achieving the max score
__global__ void k_best(const int* __restrict__ labels, const int* __restrict__ sel,
                       const float* __restrict__ scores, const unsigned int* __restrict__ compMaxU,
                       int* __restrict__ compBest) {
    int b = blockIdx.y;
    int n = blockIdx.x * blockDim.x + threadIdx.x;
    if (n >= NDIM) return;
    if (!sel[b * NN + n]) return;
    int lab = labels[b * NN + n];
    if (scores[b * NN + n] >= __uint_as_float(compMaxU[b * NN + lab]))
        atomicMin(&compBest[b * NN + lab], n);
}

// K8: rank seeded roots ascending (= reference argsort order), emit seedNode list
__global__ void k_rank(const int* __restrict__ compBest, int* __restrict__ seedNode,
                       int* __restrict__ Scnt) {
    int b = blockIdx.x, t = threadIdx.x;
    __shared__ int sh[1024];
    __shared__ int sbase;
    if (t == 0) sbase = 0;
    __syncthreads();
    for (int base = 0; base < NDIM; base += 1024) {
        int r = base + t;
        int cb = (r < NDIM) ? compBest[b * NN + r] : 0x7fffffff;
        int f = (cb != 0x7fffffff) ? 1 : 0;
        sh[t] = f;
        __syncthreads();
        for (int off = 1; off < 1024; off <<= 1) {
            int v = (t >= off) ? sh[t - off] : 0;
            __syncthreads();
            sh[t] += v;
            __syncthreads();
        }
        if (f) seedNode[b * NN + sbase + sh[t] - 1] = cb;
        __syncthreads();
        if (t == 0) sbase += sh[1023];
        __syncthreads();
    }
    if (t == 0) Scnt[b] = sbase;
}

// K9: write compacted seed signatures / mask / scores (out pre-zeroed)
__global__ void k_write(const float* __restrict__ sig, const float* __restrict__ scores,
                        const int* __restrict__ seedNode, const int* __restrict__ Scnt,
                        float* __restrict__ out) {
    int b = blockIdx.y;
    int slot = blockIdx.x;
    if (slot >= Scnt[b]) return;
    int s = seedNode[b * NN + slot];
    int lane = threadIdx.x;
    float4 v = *(const float4*)(sig + sig_off(b, s) + lane * 4);
    *(float4*)(out + ((size_t)(b * NDIM + slot)) * CDIM + lane * 4) = v;
    if (lane == 0) {
        out[(size_t)BDIM * NDIM * CDIM + (size_t)b * NDIM + slot] = 1.0f;
        out[(size_t)BDIM * NDIM * CDIM + (size_t)BDIM * NDIM + (size_t)b * NDIM + slot] =
            scores[b * NN + s];
    }
}

extern "C" void kernel_launch(void* const* d_in, const int* in_sizes, int n_in,
                              void* d_out, int out_size, void* d_ws, size_t ws_size,
                              hipStream_t stream) {
    (void)in_sizes; (void)n_in; (void)ws_size;
    const float* sig = (const float*)d_in[0];
    const float* logits = (const float*)d_in[1];
    float* out = (float*)d_out;
    char* ws = (char*)d_ws;

    const size_t arr = (size_t)BDIM * NN * 4;  // 86528 B per array
    int* selCount = (int*)(ws + 0);                        // 16 B
    int* Mcnt = (int*)(ws + 16);                           // 16 B
    int* Scnt = (int*)(ws + 32);                           // 16 B
    unsigned long long* argKey = (unsigned long long*)(ws + 64);  // 32 B
    unsigned int* compMaxU = (unsigned int*)(ws + 256);
    float* scores = (float*)(ws + 256 + 1 * arr);
    float* ninv   = (float*)(ws + 256 + 2 * arr);
    int* sel      = (int*)(ws + 256 + 3 * arr);
    int* parent   = (int*)(ws + 256 + 4 * arr);
    int* labels   = (int*)(ws + 256 + 5 * arr);
    int* compBest = (int*)(ws + 256 + 6 * arr);
    int* selIdx   = (int*)(ws + 256 + 7 * arr);
    int* seedNode = (int*)(ws + 256 + 8 * arr);

    // zero counters + compMaxU; zero the output (poisoned 0xAA each call)
    hipMemsetAsync(d_ws, 0, 256 + arr, stream);
    hipMemsetAsync(d_out, 0, (size_t)out_size * sizeof(float), stream);

    dim3 gN((NDIM + 255) / 256, BDIM);
    k_init<<<gN, 256, 0, stream>>>(logits, scores, sel, parent, compBest, selCount, argKey);
    k_norm<<<dim3((NDIM + 3) / 4, BDIM), 256, 0, stream>>>(sig, ninv);
    k_resolve<<<1, 64, 0, stream>>>(sel, selCount, argKey);
    k_compact<<<BDIM, 1024, 0, stream>>>(sel, selIdx, Mcnt);
    k_sim<<<dim3(NTRI, BDIM), 256, 0, stream>>>(sig, ninv, selIdx, Mcnt, parent);
    k_flatten<<<gN, 256, 0, stream>>>(parent, labels, sel, scores, compMaxU);
    k_best<<<gN, 256, 0, stream>>>(labels, sel, scores, compMaxU, compBest);
    k_rank<<<BDIM, 1024, 0, stream>>>(compBest, seedNode, Scnt);
    k_write<<<dim3(NDIM, BDIM), 64, 0, stream>>>(sig, scores, seedNode, Scnt, out);
}

// Round 2
// 176.084 us; speedup vs baseline: 1.6673x; 1.6673x over previous
//
#include <hip/hip_runtime.h>
#include <cstdint>
#include <cstddef>

#define LDIM 6
#define BDIM 4
#define QDIM 900
#define CDIM 256
#define NDIM (LDIM*QDIM)   /* 5400 */
#define NN   5408          /* padded per-image stride */
#define TT   85            /* ceil(5400/64) */
#define NTRI (TT*(TT+1)/2) /* 3655 lower-tri 64x64 tiles */

typedef short bf16x8 __attribute__((ext_vector_type(8)));
typedef float floatx4 __attribute__((ext_vector_type(4)));

__device__ __forceinline__ int sig_off(int b, int n) {
    int l = n / QDIM, q = n - l * QDIM;
    return ((l * BDIM + b) * QDIM + q) * CDIM;
}
__device__ __forceinline__ int logit_off(int b, int n) {
    int l = n / QDIM, q = n - l * QDIM;
    return (l * BDIM + b) * QDIM + q;
}

__device__ __forceinline__ int uf_load(const int* p, int i) {
    return __hip_atomic_load(&p[i], __ATOMIC_RELAXED, __HIP_MEMORY_SCOPE_AGENT);
}
__device__ int uf_find(int* p, int x) {
    int r = x;
    int pr = uf_load(p, r);
    while (pr != r) { r = pr; pr = uf_load(p, r); }
    return r;
}
__device__ void uf_union(int* p, int a, int b) {
    int ra = uf_find(p, a), rb = uf_find(p, b);
    while (ra != rb) {
        int hi = ra > rb ? ra : rb;
        int lo = ra ^ rb ^ hi;
        int old = atomicCAS(&p[hi], hi, lo);
        if (old == hi) return;
        ra = uf_find(p, old);
        rb = uf_find(p, lo);
    }
}

__device__ __forceinline__ unsigned short f2bf(float f) {
    unsigned int u = __float_as_uint(f);
    u += 0x7fffu + ((u >> 16) & 1u);   // round-to-nearest-even
    return (unsigned short)(u >> 16);
}

// K1: scores, sel flags, parent init, compBest init, per-image selCount + argmax key
__global__ void k_init(const float* __restrict__ logits, float* __restrict__ scores,
                       int* __restrict__ sel, int* __restrict__ parent,
                       int* __restrict__ compBest, int* __restrict__ selCount,
                       unsigned long long* __restrict__ argKey) {
    int b = blockIdx.y;
    int n = blockIdx.x * blockDim.x + threadIdx.x;
    unsigned long long key = 0ULL;
    int s = 0;
    if (n < NDIM) {
        float x = logits[logit_off(b, n)];
        float sc = 1.0f / (1.0f + expf(-x));
        scores[b * NN + n] = sc;
        s = (sc >= 0.5f) ? 1 : 0;
        sel[b * NN + n] = s;
        parent[b * NN + n] = n;
        compBest[b * NN + n] = 0x7fffffff;
        key = ((unsigned long long)__float_as_uint(sc) << 32) | (unsigned int)(~n);
    }
    unsigned long long bal = __ballot(s != 0);
    int cnt = __popcll(bal);
    for (int off = 32; off; off >>= 1) {
        unsigned long long o = __shfl_down(key, off);
        if (o > key) key = o;
    }
    if ((threadIdx.x & 63) == 0) {
        if (cnt) atomicAdd(&selCount[b], cnt);
        atomicMax(&argKey[b], key);
    }
}

// K2 (fallback path only): inverse norms, one wave per node
__global__ void k_norm(const float* __restrict__ sig, float* __restrict__ ninv) {
    int b = blockIdx.y;
    int wave = (blockIdx.x * blockDim.x + threadIdx.x) >> 6;
    int lane = threadIdx.x & 63;
    if (wave >= NDIM) return;
    const float4 v = *(const float4*)(sig + sig_off(b, wave) + lane * 4);
    float s = v.x * v.x + v.y * v.y + v.z * v.z + v.w * v.w;
    for (int off = 32; off; off >>= 1) s += __shfl_down(s, off);
    if (lane == 0) ninv[b * NN + wave] = rsqrtf(s + 1e-12f);
}

// K3: fallback argmax select if nothing passed the threshold
__global__ void k_resolve(int* __restrict__ sel, int* __restrict__ selCount,
                          const unsigned long long* __restrict__ argKey) {
    int b = threadIdx.x;
    if (b >= BDIM) return;
    if (selCount[b] == 0) {
        int n = (int)(~(unsigned int)(argKey[b] & 0xffffffffULL));
        sel[b * NN + n] = 1;
        selCount[b] = 1;
    }
}

// K4: ordered compaction of selected node indices — ballot/popc scan, 1024 thr/image
__global__ void k_compact(const int* __restrict__ sel, int* __restrict__ selIdx,
                          int* __restrict__ Mcnt) {
    int b = blockIdx.x, t = threadIdx.x;
    int lane = t & 63, w = t >> 6;               // 16 waves
    __shared__ int wsum[16];
    __shared__ int sbase;
    if (t == 0) sbase = 0;
    __syncthreads();
    for (int base = 0; base < NDIM; base += 1024) {
        int n = base + t;
        int f = (n < NDIM) ? sel[b * NN + n] : 0;
        unsigned long long bal = __ballot(f != 0);
        int rank = __popcll(bal & ((1ull << lane) - 1ull));
        if (lane == 0) wsum[w] = __popcll(bal);
        __syncthreads();
        if (t == 0) {
            int s = sbase;
            for (int i = 0; i < 16; i++) { int v = wsum[i]; wsum[i] = s; s += v; }
            sbase = s;
        }
        __syncthreads();
        if (f) selIdx[b * NN + wsum[w] + rank] = n;
        __syncthreads();
    }
    if (t == 0) Mcnt[b] = sbase;
}

// K4b: normalize + fp32->bf16 compaction: Xbf[b][g][c] = bf16(sig[node_g]*ninv), one wave/row
__global__ void k_tobf(const float* __restrict__ sig, const int* __restrict__ selIdx,
                       const int* __restrict__ Mcnt, unsigned short* __restrict__ Xbf) {
    int b = blockIdx.y;
    int g = (blockIdx.x * blockDim.x + threadIdx.x) >> 6;
    int lane = threadIdx.x & 63;
    if (g >= Mcnt[b]) return;
    int node = selIdx[b * NN + g];
    const float4 v = *(const float4*)(sig + sig_off(b, node) + lane * 4);
    float s = v.x * v.x + v.y * v.y + v.z * v.z + v.w * v.w;
    for (int off = 32; off; off >>= 1) s += __shfl_down(s, off);
    s = __shfl(s, 0);
    float ninv = rsqrtf(s + 1e-12f);
    ushort4 o;
    o.x = f2bf(v.x * ninv); o.y = f2bf(v.y * ninv);
    o.z = f2bf(v.z * ninv); o.w = f2bf(v.w * ninv);
    *(ushort4*)(Xbf + ((size_t)(b * NN + g)) * CDIM + lane * 4) = o;
}

// K5: MFMA pairwise sims over compacted normalized bf16 rows (lower-tri 64x64 tiles)
__global__ __launch_bounds__(256) void k_sim_mfma(const unsigned short* __restrict__ Xbf,
                                                  const int* __restrict__ selIdx,
                                                  const int* __restrict__ Mcnt,
                                                  int* __restrict__ parent) {
    int b = blockIdx.y;
    int M = Mcnt[b];
    int t = blockIdx.x;
    int ti = (int)((sqrtf(8.0f * (float)t + 1.0f) - 1.0f) * 0.5f);
    while ((ti + 1) * (ti + 2) / 2 <= t) ti++;
    while (ti * (ti + 1) / 2 > t) ti--;
    int tj = t - ti * (ti + 1) / 2;
    if (ti * 64 >= M) return;

    int tid = threadIdx.x;
    int lane = tid & 63, wave = tid >> 6;
    int rsel = lane & 15, quad = lane >> 4;

    // A fragment rows: wave's 16-row slab of the ti block
    int gA = min(ti * 64 + wave * 16 + rsel, M - 1);
    const unsigned short* pA = Xbf + ((size_t)(b * NN + gA)) * CDIM + quad * 8;
    const unsigned short* pB[4];
#pragma unroll
    for (int nj = 0; nj < 4; nj++) {
        int gB = min(tj * 64 + nj * 16 + rsel, M - 1);
        pB[nj] = Xbf + ((size_t)(b * NN + gB)) * CDIM + quad * 8;
    }

    floatx4 acc[4] = {{0.f,0.f,0.f,0.f},{0.f,0.f,0.f,0.f},{0.f,0.f,0.f,0.f},{0.f,0.f,0.f,0.f}};
#pragma unroll
    for (int ks = 0; ks < CDIM / 32; ks++) {
        bf16x8 a = *(const bf16x8*)(pA + ks * 32);
#pragma unroll
        for (int nj = 0; nj < 4; nj++) {
            bf16x8 bb = *(const bf16x8*)(pB[nj] + ks * 32);
            acc[nj] = __builtin_amdgcn_mfma_f32_16x16x32_bf16(a, bb, acc[nj], 0, 0, 0);
        }
    }

    int rowA = ti * 64 + wave * 16 + quad * 4;
#pragma unroll
    for (int nj = 0; nj < 4; nj++) {
        int gj = tj * 64 + nj * 16 + rsel;
#pragma unroll
        for (int r = 0; r < 4; r++) {
            int gi = rowA + r;
            if (gi < M && gj < M && gi > gj && acc[nj][r] >= 0.8f) {
                uf_union(parent + b * NN, selIdx[b * NN + gi], selIdx[b * NN + gj]);
            }
        }
    }
}

// K5-fallback: fp32 LDS-tiled sims (used only if ws too small for Xbf)
__global__ __launch_bounds__(256) void k_sim(const float* __restrict__ sig,
                                             const float* __restrict__ ninv,
                                             const int* __restrict__ selIdx,
                                             const int* __restrict__ Mcnt,
                                             int* __restrict__ parent) {
    int b = blockIdx.y;
    int M = Mcnt[b];
    int t = blockIdx.x;
    int ti = (int)((sqrtf(8.0f * (float)t + 1.0f) - 1.0f) * 0.5f);
    while ((ti + 1) * (ti + 2) / 2 <= t) ti++;
    while (ti * (ti + 1) / 2 > t) ti--;
    int tj = t - ti * (ti + 1) / 2;
    if (ti * 64 >= M) return;

    __shared__ float As[64][17], Bs[64][17];
    __shared__ int idxA[64], idxB[64], offA[64], offB[64];
    __shared__ float nvA[64], nvB[64];

    int tid = threadIdx.x;
    if (tid < 64) {
        int g = min(ti * 64 + tid, M - 1);
        int node = selIdx[b * NN + g];
        idxA[tid] = node; offA[tid] = sig_off(b, node); nvA[tid] = ninv[b * NN + node];
    } else if (tid < 128) {
        int lid = tid - 64;
        int g = min(tj * 64 + lid, M - 1);
        int node = selIdx[b * NN + g];
        idxB[lid] = node; offB[lid] = sig_off(b, node); nvB[lid] = ninv[b * NN + node];
    }
    __syncthreads();

    float acc[4][4] = {};
    int r = tid >> 2;
    int c4 = (tid & 3) * 4;
    int i0 = (tid >> 4) * 4;
    int j0 = (tid & 15) * 4;

    for (int k0 = 0; k0 < CDIM; k0 += 16) {
        float4 a = *(const float4*)(sig + offA[r] + k0 + c4);
        float4 bb = *(const float4*)(sig + offB[r] + k0 + c4);
        As[r][c4 + 0] = a.x; As[r][c4 + 1] = a.y; As[r][c4 + 2] = a.z; As[r][c4 + 3] = a.w;
        Bs[r][c4 + 0] = bb.x; Bs[r][c4 + 1] = bb.y; Bs[r][c4 + 2] = bb.z; Bs[r][c4 + 3] = bb.w;
        __syncthreads();
#pragma unroll
        for (int kk = 0; kk < 16; kk++) {
            float av[4], bv[4];
#pragma unroll
            for (int x = 0; x < 4; x++) { av[x] = As[i0 + x][kk]; bv[x] = Bs[j0 + x][kk]; }
#pragma unroll
            for (int x = 0; x < 4; x++)
#pragma unroll
                for (int y = 0; y < 4; y++) acc[x][y] += av[x] * bv[y];
        }
        __syncthreads();
    }

#pragma unroll
    for (int x = 0; x < 4; x++)
#pragma unroll
        for (int y = 0; y < 4; y++) {
            int gi = ti * 64 + i0 + x, gj = tj * 64 + j0 + y;
            if (gi < M && gj < M && gi > gj) {
                float sim = acc[x][y] * nvA[i0 + x] * nvB[j0 + y];
                if (sim >= 0.8f) uf_union(parent + b * NN, idxA[i0 + x], idxB[j0 + y]);
            }
        }
}

// K6: flatten labels + per-component max score
__global__ void k_flatten(const int* __restrict__ parent, int* __restrict__ labels,
                          const int* __restrict__ sel, const float* __restrict__ scores,
                          unsigned int* __restrict__ compMaxU) {
    int b = blockIdx.y;
    int n = blockIdx.x * blockDim.x + threadIdx.x;
    if (n >= NDIM) return;
    int r = n, pr = parent[b * NN + r];
    while (pr != r) { r = pr; pr = parent[b * NN + r]; }
    labels[b * NN + n] = r;
    if (sel[b * NN + n])
        atomicMax(&compMaxU[b * NN + r], __float_as_uint(scores[b * NN + n]));
}

// K7: per-component smallest index achieving the max score
__global__ void k_best(const int* __restrict__ labels, const int* __restrict__ sel,
                       const float* __restrict__ scores, const unsigned int* __restrict__ compMaxU,
                       int* __restrict__ compBest) {
    int b = blockIdx.y;
    int n = blockIdx.x * blockDim.x + threadIdx.x;
    if (n >= NDIM) return;
    if (!sel[b * NN + n]) return;
    int lab = labels[b * NN + n];
    if (scores[b * NN + n] >= __uint_as_float(compMaxU[b * NN + lab]))
        atomicMin(&compBest[b * NN + lab], n);
}

// K8: rank seeded roots ascending, emit seedNode list — ballot/popc scan
__global__ void k_rank(const int* __restrict__ compBest, int* __restrict__ seedNode,
                       int* __restrict__ Scnt) {
    int b = blockIdx.x, t = threadIdx.x;
    int lane = t & 63, w = t >> 6;
    __shared__ int wsum[16];
    __shared__ int sbase;
    if (t == 0) sbase = 0;
    __syncthreads();
    for (int base = 0; base < NDIM; base += 1024) {
        int n = base + t;
        int cb = (n < NDIM) ? compBest[b * NN + n] : 0x7fffffff;
        int f = (cb != 0x7fffffff) ? 1 : 0;
        unsigned long long bal = __ballot(f != 0);
        int rank = __popcll(bal & ((1ull << lane) - 1ull));
        if (lane == 0) wsum[w] = __popcll(bal);
        __syncthreads();
        if (t == 0) {
            int s = sbase;
            for (int i = 0; i < 16; i++) { int v = wsum[i]; wsum[i] = s; s += v; }
            sbase = s;
        }
        __syncthreads();
        if (f) seedNode[b * NN + wsum[w] + rank] = cb;
        __syncthreads();
    }
    if (t == 0) Scnt[b] = sbase;
}

// K9: write compacted seed signatures / mask / scores (out pre-zeroed)
__global__ void k_write(const float* __restrict__ sig, const float* __restrict__ scores,
                        const int* __restrict__ seedNode, const int* __restrict__ Scnt,
                        float* __restrict__ out) {
    int b = blockIdx.y;
    int slot = blockIdx.x;
    if (slot >= Scnt[b]) return;
    int s = seedNode[b * NN + slot];
    int lane = threadIdx.x;
    float4 v = *(const float4*)(sig + sig_off(b, s) + lane * 4);
    *(float4*)(out + ((size_t)(b * NDIM + slot)) * CDIM + lane * 4) = v;
    if (lane == 0) {
        out[(size_t)BDIM * NDIM * CDIM + (size_t)b * NDIM + slot] = 1.0f;
        out[(size_t)BDIM * NDIM * CDIM + (size_t)BDIM * NDIM + (size_t)b * NDIM + slot] =
            scores[b * NN + s];
    }
}

extern "C" void kernel_launch(void* const* d_in, const int* in_sizes, int n_in,
                              void* d_out, int out_size, void* d_ws, size_t ws_size,
                              hipStream_t stream) {
    (void)in_sizes; (void)n_in;
    const float* sig = (const float*)d_in[0];
    const float* logits = (const float*)d_in[1];
    float* out = (float*)d_out;
    char* ws = (char*)d_ws;

    const size_t arr = (size_t)BDIM * NN * 4;  // 86528 B per array
    int* selCount = (int*)(ws + 0);
    int* Mcnt = (int*)(ws + 16);
    int* Scnt = (int*)(ws + 32);
    unsigned long long* argKey = (unsigned long long*)(ws + 64);
    unsigned int* compMaxU = (unsigned int*)(ws + 256);
    float* scores = (float*)(ws + 256 + 1 * arr);
    int* sel      = (int*)(ws + 256 + 2 * arr);
    int* parent   = (int*)(ws + 256 + 3 * arr);
    int* labels   = (int*)(ws + 256 + 4 * arr);
    int* compBest = (int*)(ws + 256 + 5 * arr);
    int* selIdx   = (int*)(ws + 256 + 6 * arr);
    int* seedNode = (int*)(ws + 256 + 7 * arr);
    float* ninv   = (float*)(ws + 256 + 8 * arr);      // fallback path only
    unsigned short* Xbf = (unsigned short*)(ws + 256 + 9 * arr);
    const size_t need_bf = 256 + 9 * arr + (size_t)BDIM * NN * CDIM * 2;  // ~11.9 MB

    hipMemsetAsync(d_ws, 0, 256 + arr, stream);  // counters + compMaxU
    hipMemsetAsync(d_out, 0, (size_t)out_size * sizeof(float), stream);

    dim3 gN((NDIM + 255) / 256, BDIM);
    k_init<<<gN, 256, 0, stream>>>(logits, scores, sel, parent, compBest, selCount, argKey);
    k_resolve<<<1, 64, 0, stream>>>(sel, selCount, argKey);
    k_compact<<<BDIM, 1024, 0, stream>>>(sel, selIdx, Mcnt);

    if (ws_size >= need_bf) {
        k_tobf<<<dim3((NDIM + 3) / 4, BDIM), 256, 0, stream>>>(sig, selIdx, Mcnt, Xbf);
        k_sim_mfma<<<dim3(NTRI, BDIM), 256, 0, stream>>>(Xbf, selIdx, Mcnt, parent);
    } else {
        k_norm<<<dim3((NDIM + 3) / 4, BDIM), 256, 0, stream>>>(sig, ninv);
        k_sim<<<dim3(NTRI, BDIM), 256, 0, stream>>>(sig, ninv, selIdx, Mcnt, parent);
    }

    k_flatten<<<gN, 256, 0, stream>>>(parent, labels, sel, scores, compMaxU);
    k_best<<<gN, 256, 0, stream>>>(labels, sel, scores, compMaxU, compBest);
    k_rank<<<BDIM, 1024, 0, stream>>>(compBest, seedNode, Scnt);
    k_write<<<dim3(NDIM, BDIM), 64, 0, stream>>>(sig, scores, seedNode, Scnt, out);
}

// Round 3
// 119.784 us; speedup vs baseline: 2.4509x; 1.4700x over previous
//
#include <hip/hip_runtime.h>
#include <cstdint>
#include <cstddef>

#define LDIM 6
#define BDIM 4
#define QDIM 900
#define CDIM 256
#define NDIM (LDIM*QDIM)   /* 5400 */
#define NN   5408          /* padded per-image stride */
#define TT   85            /* ceil(5400/64) */
#define NTRI (TT*(TT+1)/2) /* 3655 lower-tri 64x64 tiles */

typedef short bf16x8 __attribute__((ext_vector_type(8)));
typedef float floatx4 __attribute__((ext_vector_type(4)));

__device__ __forceinline__ int sig_off(int b, int n) {
    int l = n / QDIM, q = n - l * QDIM;
    return ((l * BDIM + b) * QDIM + q) * CDIM;
}
__device__ __forceinline__ int logit_off(int b, int n) {
    int l = n / QDIM, q = n - l * QDIM;
    return (l * BDIM + b) * QDIM + q;
}

__device__ __forceinline__ int uf_load(const int* p, int i) {
    return __hip_atomic_load(&p[i], __ATOMIC_RELAXED, __HIP_MEMORY_SCOPE_AGENT);
}
__device__ int uf_find(int* p, int x) {
    int r = x;
    int pr = uf_load(p, r);
    while (pr != r) { r = pr; pr = uf_load(p, r); }
    return r;
}
__device__ void uf_union(int* p, int a, int b) {
    int ra = uf_find(p, a), rb = uf_find(p, b);
    while (ra != rb) {
        int hi = ra > rb ? ra : rb;
        int lo = ra ^ rb ^ hi;
        int old = atomicCAS(&p[hi], hi, lo);
        if (old == hi) return;
        ra = uf_find(p, old);
        rb = uf_find(p, lo);
    }
}

__device__ __forceinline__ unsigned short f2bf(float f) {
    unsigned int u = __float_as_uint(f);
    u += 0x7fffu + ((u >> 16) & 1u);   // round-to-nearest-even
    return (unsigned short)(u >> 16);
}

// K1: scores, sel flags, parent init, per-image argmax key
__global__ void k_init(const float* __restrict__ logits, float* __restrict__ scores,
                       int* __restrict__ sel, int* __restrict__ parent,
                       unsigned long long* __restrict__ argKey) {
    int b = blockIdx.y;
    int n = blockIdx.x * blockDim.x + threadIdx.x;
    unsigned long long key = 0ULL;
    if (n < NDIM) {
        float x = logits[logit_off(b, n)];
        float sc = 1.0f / (1.0f + expf(-x));
        scores[b * NN + n] = sc;
        sel[b * NN + n] = (sc >= 0.5f) ? 1 : 0;
        parent[b * NN + n] = n;
        key = ((unsigned long long)__float_as_uint(sc) << 32) | (unsigned int)(~n);
    }
    for (int off = 32; off; off >>= 1) {
        unsigned long long o = __shfl_down(key, off);
        if (o > key) key = o;
    }
    if ((threadIdx.x & 63) == 0) atomicMax(&argKey[b], key);
}

// K2: ordered compaction of selected node indices + argmax fallback fused
__global__ void k_compact(int* __restrict__ sel, int* __restrict__ selIdx,
                          int* __restrict__ Mcnt, const unsigned long long* __restrict__ argKey) {
    int b = blockIdx.x, t = threadIdx.x;
    int lane = t & 63, w = t >> 6;               // 16 waves
    __shared__ int wsum[16];
    __shared__ int sbase;
    if (t == 0) sbase = 0;
    __syncthreads();
    for (int base = 0; base < NDIM; base += 1024) {
        int n = base + t;
        int f = (n < NDIM) ? sel[b * NN + n] : 0;
        unsigned long long bal = __ballot(f != 0);
        int rank = __popcll(bal & ((1ull << lane) - 1ull));
        if (lane == 0) wsum[w] = __popcll(bal);
        __syncthreads();
        if (t == 0) {
            int s = sbase;
            for (int i = 0; i < 16; i++) { int v = wsum[i]; wsum[i] = s; s += v; }
            sbase = s;
        }
        __syncthreads();
        if (f) selIdx[b * NN + wsum[w] + rank] = n;
        __syncthreads();
    }
    if (t == 0) {
        if (sbase == 0) {   // fallback: argmax score
            int n = (int)(~(unsigned int)(argKey[b] & 0xffffffffULL));
            selIdx[b * NN + 0] = n;
            sel[b * NN + n] = 1;
            Mcnt[b] = 1;
        } else {
            Mcnt[b] = sbase;
        }
    }
}

// K3: normalize + fp32->bf16 compaction with per-row chunk swizzle:
// 16B chunk c of row g stored at chunk slot c ^ (g & 7)
__global__ void k_tobf(const float* __restrict__ sig, const int* __restrict__ selIdx,
                       const int* __restrict__ Mcnt, unsigned short* __restrict__ Xbf) {
    int b = blockIdx.y;
    int g = (blockIdx.x * blockDim.x + threadIdx.x) >> 6;
    int lane = threadIdx.x & 63;
    if (g >= Mcnt[b]) return;
    int node = selIdx[b * NN + g];
    const float4 v = *(const float4*)(sig + sig_off(b, node) + lane * 4);
    float s = v.x * v.x + v.y * v.y + v.z * v.z + v.w * v.w;
    for (int off = 32; off; off >>= 1) s += __shfl_down(s, off);
    s = __shfl(s, 0);
    float ninv = rsqrtf(s + 1e-12f);
    ushort4 o;
    o.x = f2bf(v.x * ninv); o.y = f2bf(v.y * ninv);
    o.z = f2bf(v.z * ninv); o.w = f2bf(v.w * ninv);
    int c = lane >> 1;                       // logical 16B chunk 0..31
    int sc = c ^ (g & 7);                    // swizzled slot
    *(ushort4*)(Xbf + ((size_t)(b * NN + g)) * CDIM + sc * 8 + (lane & 1) * 4) = o;
}

// K4: MFMA pairwise sims. B tile (64 rows) staged to LDS via global_load_lds;
// A fragments direct from global (wave-private rows, read once).
__global__ __launch_bounds__(256) void k_sim_mfma(const unsigned short* __restrict__ Xbf,
                                                  const int* __restrict__ selIdx,
                                                  const int* __restrict__ Mcnt,
                                                  int* __restrict__ parent) {
    int bx = blockIdx.x;
    int b = bx & 3;            // image -> XCD-pair locality
    int t = bx >> 2;
    int M = Mcnt[b];
    int ti = (int)((sqrtf(8.0f * (float)t + 1.0f) - 1.0f) * 0.5f);
    while ((ti + 1) * (ti + 2) / 2 <= t) ti++;
    while (ti * (ti + 1) / 2 > t) ti--;
    int tj = t - ti * (ti + 1) / 2;
    if (ti * 64 >= M) return;

    __shared__ char Bs[32768];   // 64 rows x 512 B (swizzled layout preserved)

    int tid = threadIdx.x;
    int lane = tid & 63, wave = tid >> 6;
    int rsel = lane & 15, quad = lane >> 4;

    // stage B rows [tj*64, +64): 32 x 1KB contiguous copies, 8 per wave
    const char* xb = (const char*)Xbf + ((size_t)b * NN) * 512;
#pragma unroll
    for (int k = 0; k < 8; k++) {
        int i = wave * 8 + k;
        int row = min(tj * 64 + 2 * i, NN - 2);
        const char* src = xb + (size_t)row * 512 + lane * 16;
        __builtin_amdgcn_global_load_lds(
            (const __attribute__((address_space(1))) unsigned int*)src,
            (__attribute__((address_space(3))) unsigned int*)(Bs + i * 1024),
            16, 0, 0);
    }

    // A fragment pointers (wave's 16-row slab of the ti block)
    int gA = min(ti * 64 + wave * 16 + rsel, M - 1);
    const unsigned short* pA = Xbf + ((size_t)(b * NN + gA)) * CDIM;
    int swA = gA & 7;
    int swB = rsel & 7;

    __syncthreads();   // drains global_load_lds (compiler emits vmcnt(0))

    floatx4 acc[4] = {{0.f,0.f,0.f,0.f},{0.f,0.f,0.f,0.f},{0.f,0.f,0.f,0.f},{0.f,0.f,0.f,0.f}};
#pragma unroll
    for (int ks = 0; ks < CDIM / 32; ks++) {
        bf16x8 a = *(const bf16x8*)(pA + (((ks * 4 + quad) ^ swA) << 3));
#pragma unroll
        for (int nj = 0; nj < 4; nj++) {
            const char* pb = Bs + (nj * 16 + rsel) * 512 + (((ks * 4 + quad) ^ swB) << 4);
            bf16x8 bb = *(const bf16x8*)pb;
            acc[nj] = __builtin_amdgcn_mfma_f32_16x16x32_bf16(a, bb, acc[nj], 0, 0, 0);
        }
    }

    int rowA = ti * 64 + wave * 16 + quad * 4;
#pragma unroll
    for (int nj = 0; nj < 4; nj++) {
        int gj = tj * 64 + nj * 16 + rsel;
#pragma unroll
        for (int r = 0; r < 4; r++) {
            int gi = rowA + r;
            if (gi < M && gj < M && gi > gj && acc[nj][r] >= 0.8f) {
                uf_union(parent + b * NN, selIdx[b * NN + gi], selIdx[b * NN + gj]);
            }
        }
    }
}

// K2b (fallback path only): inverse norms
__global__ void k_norm(const float* __restrict__ sig, float* __restrict__ ninv) {
    int b = blockIdx.y;
    int wave = (blockIdx.x * blockDim.x + threadIdx.x) >> 6;
    int lane = threadIdx.x & 63;
    if (wave >= NDIM) return;
    const float4 v = *(const float4*)(sig + sig_off(b, wave) + lane * 4);
    float s = v.x * v.x + v.y * v.y + v.z * v.z + v.w * v.w;
    for (int off = 32; off; off >>= 1) s += __shfl_down(s, off);
    if (lane == 0) ninv[b * NN + wave] = rsqrtf(s + 1e-12f);
}

// K4-fallback: fp32 LDS-tiled sims (used only if ws too small for Xbf)
__global__ __launch_bounds__(256) void k_sim(const float* __restrict__ sig,
                                             const float* __restrict__ ninv,
                                             const int* __restrict__ selIdx,
                                             const int* __restrict__ Mcnt,
                                             int* __restrict__ parent) {
    int b = blockIdx.y;
    int M = Mcnt[b];
    int t = blockIdx.x;
    int ti = (int)((sqrtf(8.0f * (float)t + 1.0f) - 1.0f) * 0.5f);
    while ((ti + 1) * (ti + 2) / 2 <= t) ti++;
    while (ti * (ti + 1) / 2 > t) ti--;
    int tj = t - ti * (ti + 1) / 2;
    if (ti * 64 >= M) return;

    __shared__ float As[64][17], Bs2[64][17];
    __shared__ int idxA[64], idxB[64], offA[64], offB[64];
    __shared__ float nvA[64], nvB[64];

    int tid = threadIdx.x;
    if (tid < 64) {
        int g = min(ti * 64 + tid, M - 1);
        int node = selIdx[b * NN + g];
        idxA[tid] = node; offA[tid] = sig_off(b, node); nvA[tid] = ninv[b * NN + node];
    } else if (tid < 128) {
        int lid = tid - 64;
        int g = min(tj * 64 + lid, M - 1);
        int node = selIdx[b * NN + g];
        idxB[lid] = node; offB[lid] = sig_off(b, node); nvB[lid] = ninv[b * NN + node];
    }
    __syncthreads();

    float acc[4][4] = {};
    int r = tid >> 2;
    int c4 = (tid & 3) * 4;
    int i0 = (tid >> 4) * 4;
    int j0 = (tid & 15) * 4;

    for (int k0 = 0; k0 < CDIM; k0 += 16) {
        float4 a = *(const float4*)(sig + offA[r] + k0 + c4);
        float4 bb = *(const float4*)(sig + offB[r] + k0 + c4);
        As[r][c4 + 0] = a.x; As[r][c4 + 1] = a.y; As[r][c4 + 2] = a.z; As[r][c4 + 3] = a.w;
        Bs2[r][c4 + 0] = bb.x; Bs2[r][c4 + 1] = bb.y; Bs2[r][c4 + 2] = bb.z; Bs2[r][c4 + 3] = bb.w;
        __syncthreads();
#pragma unroll
        for (int kk = 0; kk < 16; kk++) {
            float av[4], bv[4];
#pragma unroll
            for (int x = 0; x < 4; x++) { av[x] = As[i0 + x][kk]; bv[x] = Bs2[j0 + x][kk]; }
#pragma unroll
            for (int x = 0; x < 4; x++)
#pragma unroll
                for (int y = 0; y < 4; y++) acc[x][y] += av[x] * bv[y];
        }
        __syncthreads();
    }

#pragma unroll
    for (int x = 0; x < 4; x++)
#pragma unroll
        for (int y = 0; y < 4; y++) {
            int gi = ti * 64 + i0 + x, gj = tj * 64 + j0 + y;
            if (gi < M && gj < M && gi > gj) {
                float sim = acc[x][y] * nvA[i0 + x] * nvB[j0 + y];
                if (sim >= 0.8f) uf_union(parent + b * NN, idxA[i0 + x], idxB[j0 + y]);
            }
        }
}

// K5: flatten labels + per-component packed argmax key (score, then min index)
__global__ void k_flatten(const int* __restrict__ parent, const int* __restrict__ sel,
                          const float* __restrict__ scores,
                          unsigned long long* __restrict__ compKey) {
    int b = blockIdx.y;
    int n = blockIdx.x * blockDim.x + threadIdx.x;
    if (n >= NDIM) return;
    if (!sel[b * NN + n]) return;
    int r = n, pr = parent[b * NN + r];
    while (pr != r) { r = pr; pr = parent[b * NN + r]; }
    unsigned long long key =
        ((unsigned long long)__float_as_uint(scores[b * NN + n]) << 32) | (unsigned int)(~n);
    atomicMax(&compKey[b * NN + r], key);
}

// K6: rank seeded roots ascending, emit seedNode list
__global__ void k_rank(const unsigned long long* __restrict__ compKey,
                       int* __restrict__ seedNode, int* __restrict__ Scnt) {
    int b = blockIdx.x, t = threadIdx.x;
    int lane = t & 63, w = t >> 6;
    __shared__ int wsum[16];
    __shared__ int sbase;
    if (t == 0) sbase = 0;
    __syncthreads();
    for (int base = 0; base < NDIM; base += 1024) {
        int n = base + t;
        unsigned long long key = (n < NDIM) ? compKey[b * NN + n] : 0ULL;
        int f = (key != 0ULL) ? 1 : 0;
        unsigned long long bal = __ballot(f != 0);
        int rank = __popcll(bal & ((1ull << lane) - 1ull));
        if (lane == 0) wsum[w] = __popcll(bal);
        __syncthreads();
        if (t == 0) {
            int s = sbase;
            for (int i = 0; i < 16; i++) { int v = wsum[i]; wsum[i] = s; s += v; }
            sbase = s;
        }
        __syncthreads();
        if (f) seedNode[b * NN + wsum[w] + rank] = (int)(~(unsigned int)(key & 0xffffffffULL));
        __syncthreads();
    }
    if (t == 0) Scnt[b] = sbase;
}

// K7: write seed signatures / mask / scores; zero-fill empty slots (replaces d_out memset)
__global__ void k_write(const float* __restrict__ sig, const float* __restrict__ scores,
                        const int* __restrict__ seedNode, const int* __restrict__ Scnt,
                        float* __restrict__ out) {
    int b = blockIdx.y;
    int slot = blockIdx.x;
    int lane = threadIdx.x;
    float* orow = out + ((size_t)(b * NDIM + slot)) * CDIM + lane * 4;
    if (slot < Scnt[b]) {
        int s = seedNode[b * NN + slot];
        float4 v = *(const float4*)(sig + sig_off(b, s) + lane * 4);
        *(float4*)orow = v;
        if (lane == 0) {
            out[(size_t)BDIM * NDIM * CDIM + (size_t)b * NDIM + slot] = 1.0f;
            out[(size_t)BDIM * NDIM * CDIM + (size_t)BDIM * NDIM + (size_t)b * NDIM + slot] =
                scores[b * NN + s];
        }
    } else {
        float4 z = {0.f, 0.f, 0.f, 0.f};
        *(float4*)orow = z;
        if (lane == 0) {
            out[(size_t)BDIM * NDIM * CDIM + (size_t)b * NDIM + slot] = 0.0f;
            out[(size_t)BDIM * NDIM * CDIM + (size_t)BDIM * NDIM + (size_t)b * NDIM + slot] = 0.0f;
        }
    }
}

extern "C" void kernel_launch(void* const* d_in, const int* in_sizes, int n_in,
                              void* d_out, int out_size, void* d_ws, size_t ws_size,
                              hipStream_t stream) {
    (void)in_sizes; (void)n_in; (void)out_size;
    const float* sig = (const float*)d_in[0];
    const float* logits = (const float*)d_in[1];
    float* out = (float*)d_out;
    char* ws = (char*)d_ws;

    const size_t arr = (size_t)BDIM * NN * 4;  // 86528 B per int/float array
    int* Mcnt = (int*)(ws + 16);
    int* Scnt = (int*)(ws + 32);
    unsigned long long* argKey = (unsigned long long*)(ws + 64);
    unsigned long long* compKey = (unsigned long long*)(ws + 256);   // 2*arr bytes
    float* scores = (float*)(ws + 256 + 2 * arr);
    int* sel      = (int*)(ws + 256 + 3 * arr);
    int* parent   = (int*)(ws + 256 + 4 * arr);
    int* selIdx   = (int*)(ws + 256 + 5 * arr);
    int* seedNode = (int*)(ws + 256 + 6 * arr);
    unsigned short* Xbf = (unsigned short*)(ws + 256 + 7 * arr);
    float* ninv   = (float*)(ws + 256 + 7 * arr);      // fallback path only (aliases Xbf)
    const size_t need_bf = 256 + 7 * arr + (size_t)BDIM * NN * CDIM * 2;  // ~11.7 MB

    // zero counters + compKey only (out is zero-filled by k_write)
    hipMemsetAsync(d_ws, 0, 256 + 2 * arr, stream);

    dim3 gN((NDIM + 255) / 256, BDIM);
    k_init<<<gN, 256, 0, stream>>>(logits, scores, sel, parent, argKey);
    k_compact<<<BDIM, 1024, 0, stream>>>(sel, selIdx, Mcnt, argKey);

    if (ws_size >= need_bf) {
        k_tobf<<<dim3((NDIM + 3) / 4, BDIM), 256, 0, stream>>>(sig, selIdx, Mcnt, Xbf);
        k_sim_mfma<<<NTRI * BDIM, 256, 0, stream>>>(Xbf, selIdx, Mcnt, parent);
    } else {
        k_norm<<<dim3((NDIM + 3) / 4, BDIM), 256, 0, stream>>>(sig, ninv);
        k_sim<<<dim3(NTRI, BDIM), 256, 0, stream>>>(sig, ninv, selIdx, Mcnt, parent);
    }

    k_flatten<<<gN, 256, 0, stream>>>(parent, sel, scores, compKey);
    k_rank<<<BDIM, 1024, 0, stream>>>(compKey, seedNode, Scnt);
    k_write<<<dim3(NDIM, BDIM), 64, 0, stream>>>(sig, scores, seedNode, Scnt, out);
}

// Round 4
// 115.726 us; speedup vs baseline: 2.5369x; 1.0351x over previous
//
#include <hip/hip_runtime.h>
#include <cstdint>
#include <cstddef>

#define LDIM 6
#define BDIM 4
#define QDIM 900
#define CDIM 256
#define NDIM (LDIM*QDIM)   /* 5400 */
#define NN   5408          /* padded per-image stride */
#define TT   85            /* ceil(5400/64) */
#define NTRI (TT*(TT+1)/2) /* 3655 lower-tri 64x64 tiles */

typedef short bf16x8 __attribute__((ext_vector_type(8)));
typedef float floatx4 __attribute__((ext_vector_type(4)));

__device__ __forceinline__ int sig_off(int b, int n) {
    int l = n / QDIM, q = n - l * QDIM;
    return ((l * BDIM + b) * QDIM + q) * CDIM;
}
__device__ __forceinline__ int logit_off(int b, int n) {
    int l = n / QDIM, q = n - l * QDIM;
    return (l * BDIM + b) * QDIM + q;
}

__device__ __forceinline__ int uf_load(const int* p, int i) {
    return __hip_atomic_load(&p[i], __ATOMIC_RELAXED, __HIP_MEMORY_SCOPE_AGENT);
}
__device__ int uf_find(int* p, int x) {
    int r = x;
    int pr = uf_load(p, r);
    while (pr != r) { r = pr; pr = uf_load(p, r); }
    return r;
}
__device__ void uf_union(int* p, int a, int b) {
    int ra = uf_find(p, a), rb = uf_find(p, b);
    while (ra != rb) {
        int hi = ra > rb ? ra : rb;
        int lo = ra ^ rb ^ hi;
        int old = atomicCAS(&p[hi], hi, lo);
        if (old == hi) return;
        ra = uf_find(p, old);
        rb = uf_find(p, lo);
    }
}

__device__ __forceinline__ unsigned short f2bf(float f) {
    unsigned int u = __float_as_uint(f);
    u += 0x7fffu + ((u >> 16) & 1u);   // round-to-nearest-even
    return (unsigned short)(u >> 16);
}

// K1: fused init + ordered compaction + argmax fallback. One 1024-thr block per image.
// Writes scores, parent, selIdx, Mcnt. No sel array, no global argKey, no memset needed.
__global__ __launch_bounds__(1024) void k_prep(const float* __restrict__ logits,
                                               float* __restrict__ scores,
                                               int* __restrict__ parent,
                                               int* __restrict__ selIdx,
                                               int* __restrict__ Mcnt) {
    int b = blockIdx.x, t = threadIdx.x;
    int lane = t & 63, w = t >> 6;               // 16 waves
    __shared__ int wsum[16];
    __shared__ unsigned long long wkey[16];
    __shared__ int sbase;
    if (t == 0) sbase = 0;
    unsigned long long mykey = 0ULL;
    __syncthreads();
    for (int base = 0; base < NDIM; base += 1024) {
        int n = base + t;
        int f = 0;
        if (n < NDIM) {
            float x = logits[logit_off(b, n)];
            float sc = 1.0f / (1.0f + expf(-x));
            scores[b * NN + n] = sc;
            parent[b * NN + n] = n;
            f = (sc >= 0.5f) ? 1 : 0;
            unsigned long long key =
                ((unsigned long long)__float_as_uint(sc) << 32) | (unsigned int)(~n);
            if (key > mykey) mykey = key;
        }
        unsigned long long bal = __ballot(f != 0);
        int rank = __popcll(bal & ((1ull << lane) - 1ull));
        if (lane == 0) wsum[w] = __popcll(bal);
        __syncthreads();
        if (t == 0) {
            int s = sbase;
            for (int i = 0; i < 16; i++) { int v = wsum[i]; wsum[i] = s; s += v; }
            sbase = s;
        }
        __syncthreads();
        if (f) selIdx[b * NN + wsum[w] + rank] = n;
        __syncthreads();
    }
    // block-level argmax key (for the nothing-selected fallback)
    for (int off = 32; off; off >>= 1) {
        unsigned long long o = __shfl_down(mykey, off);
        if (o > mykey) mykey = o;
    }
    if (lane == 0) wkey[w] = mykey;
    __syncthreads();
    if (t == 0) {
        if (sbase == 0) {
            unsigned long long k = 0ULL;
            for (int i = 0; i < 16; i++) if (wkey[i] > k) k = wkey[i];
            selIdx[b * NN + 0] = (int)(~(unsigned int)(k & 0xffffffffULL));
            Mcnt[b] = 1;
        } else {
            Mcnt[b] = sbase;
        }
    }
}

// K2: normalize + fp32->bf16 compaction with per-row chunk swizzle:
// 16B chunk c of row g stored at chunk slot c ^ (g & 7)
__global__ void k_tobf(const float* __restrict__ sig, const int* __restrict__ selIdx,
                       const int* __restrict__ Mcnt, unsigned short* __restrict__ Xbf) {
    int b = blockIdx.y;
    int g = (blockIdx.x * blockDim.x + threadIdx.x) >> 6;
    int lane = threadIdx.x & 63;
    if (g >= Mcnt[b]) return;
    int node = selIdx[b * NN + g];
    const float4 v = *(const float4*)(sig + sig_off(b, node) + lane * 4);
    float s = v.x * v.x + v.y * v.y + v.z * v.z + v.w * v.w;
    for (int off = 32; off; off >>= 1) s += __shfl_down(s, off);
    s = __shfl(s, 0);
    float ninv = rsqrtf(s + 1e-12f);
    ushort4 o;
    o.x = f2bf(v.x * ninv); o.y = f2bf(v.y * ninv);
    o.z = f2bf(v.z * ninv); o.w = f2bf(v.w * ninv);
    int c = lane >> 1;                       // logical 16B chunk 0..31
    int sc = c ^ (g & 7);                    // swizzled slot
    *(ushort4*)(Xbf + ((size_t)(b * NN + g)) * CDIM + sc * 8 + (lane & 1) * 4) = o;
}

// K3: MFMA pairwise sims. B tile (64 rows) staged to LDS via global_load_lds;
// A fragments direct from global (wave-private rows, read once).
__global__ __launch_bounds__(256) void k_sim_mfma(const unsigned short* __restrict__ Xbf,
                                                  const int* __restrict__ selIdx,
                                                  const int* __restrict__ Mcnt,
                                                  int* __restrict__ parent) {
    int bx = blockIdx.x;
    int b = bx & 3;            // image -> XCD locality
    int t = bx >> 2;
    int M = Mcnt[b];
    int ti = (int)((sqrtf(8.0f * (float)t + 1.0f) - 1.0f) * 0.5f);
    while ((ti + 1) * (ti + 2) / 2 <= t) ti++;
    while (ti * (ti + 1) / 2 > t) ti--;
    int tj = t - ti * (ti + 1) / 2;
    if (ti * 64 >= M) return;

    __shared__ char Bs[32768];   // 64 rows x 512 B (swizzled layout preserved)

    int tid = threadIdx.x;
    int lane = tid & 63, wave = tid >> 6;
    int rsel = lane & 15, quad = lane >> 4;

    // stage B rows [tj*64, +64): 32 x 1KB contiguous copies, 8 per wave
    const char* xb = (const char*)Xbf + ((size_t)b * NN) * 512;
#pragma unroll
    for (int k = 0; k < 8; k++) {
        int i = wave * 8 + k;
        int row = min(tj * 64 + 2 * i, NN - 2);
        const char* src = xb + (size_t)row * 512 + lane * 16;
        __builtin_amdgcn_global_load_lds(
            (const __attribute__((address_space(1))) unsigned int*)src,
            (__attribute__((address_space(3))) unsigned int*)(Bs + i * 1024),
            16, 0, 0);
    }

    // A fragment pointers (wave's 16-row slab of the ti block)
    int gA = min(ti * 64 + wave * 16 + rsel, M - 1);
    const unsigned short* pA = Xbf + ((size_t)(b * NN + gA)) * CDIM;
    int swA = gA & 7;
    int swB = rsel & 7;

    __syncthreads();   // drains global_load_lds

    floatx4 acc[4] = {{0.f,0.f,0.f,0.f},{0.f,0.f,0.f,0.f},{0.f,0.f,0.f,0.f},{0.f,0.f,0.f,0.f}};
#pragma unroll
    for (int ks = 0; ks < CDIM / 32; ks++) {
        bf16x8 a = *(const bf16x8*)(pA + (((ks * 4 + quad) ^ swA) << 3));
#pragma unroll
        for (int nj = 0; nj < 4; nj++) {
            const char* pb = Bs + (nj * 16 + rsel) * 512 + (((ks * 4 + quad) ^ swB) << 4);
            bf16x8 bb = *(const bf16x8*)pb;
            acc[nj] = __builtin_amdgcn_mfma_f32_16x16x32_bf16(a, bb, acc[nj], 0, 0, 0);
        }
    }

    int rowA = ti * 64 + wave * 16 + quad * 4;
#pragma unroll
    for (int nj = 0; nj < 4; nj++) {
        int gj = tj * 64 + nj * 16 + rsel;
#pragma unroll
        for (int r = 0; r < 4; r++) {
            int gi = rowA + r;
            if (gi < M && gj < M && gi > gj && acc[nj][r] >= 0.8f) {
                uf_union(parent + b * NN, selIdx[b * NN + gi], selIdx[b * NN + gj]);
            }
        }
    }
}

// K4: fused component stats + ranking. One 1024-thr block per image.
// Phase 0: zero compKey. Phase 1: flatten over selIdx, atomicMax packed key per root.
// Phase 2: ballot-scan of seeded roots ascending -> seedNode, Scnt.
__global__ __launch_bounds__(1024) void k_comp(int* __restrict__ parent,
                                               const int* __restrict__ selIdx,
                                               const int* __restrict__ Mcnt,
                                               const float* __restrict__ scores,
                                               unsigned long long* __restrict__ compKey,
                                               int* __restrict__ seedNode,
                                               int* __restrict__ Scnt) {
    int b = blockIdx.x, t = threadIdx.x;
    int lane = t & 63, w = t >> 6;
    __shared__ int wsum[16];
    __shared__ int sbase;

    // phase 0: zero this image's compKey slice
    for (int n = t; n < NN; n += 1024) compKey[b * NN + n] = 0ULL;
    if (t == 0) sbase = 0;
    __syncthreads();

    // phase 1: per selected node, find root, max packed (score, ~idx) key
    int M = Mcnt[b];
    for (int base = 0; base < M; base += 1024) {
        int g = base + t;
        if (g < M) {
            int node = selIdx[b * NN + g];
            int root = uf_find(parent + b * NN, node);
            unsigned long long key =
                ((unsigned long long)__float_as_uint(scores[b * NN + node]) << 32) |
                (unsigned int)(~node);
            atomicMax(&compKey[b * NN + root], key);
        }
    }
    __syncthreads();

    // phase 2: rank seeded roots ascending (agent-scope loads to bypass stale L1)
    for (int base = 0; base < NDIM; base += 1024) {
        int n = base + t;
        unsigned long long key = 0ULL;
        if (n < NDIM)
            key = __hip_atomic_load(&compKey[b * NN + n], __ATOMIC_RELAXED,
                                    __HIP_MEMORY_SCOPE_AGENT);
        int f = (key != 0ULL) ? 1 : 0;
        unsigned long long bal = __ballot(f != 0);
        int rank = __popcll(bal & ((1ull << lane) - 1ull));
        if (lane == 0) wsum[w] = __popcll(bal);
        __syncthreads();
        if (t == 0) {
            int s = sbase;
            for (int i = 0; i < 16; i++) { int v = wsum[i]; wsum[i] = s; s += v; }
            sbase = s;
        }
        __syncthreads();
        if (f) seedNode[b * NN + wsum[w] + rank] = (int)(~(unsigned int)(key & 0xffffffffULL));
        __syncthreads();
    }
    if (t == 0) Scnt[b] = sbase;
}

// K5: write seed signatures / mask / scores; zero-fill empty slots. 4 rows per block.
__global__ void k_write(const float* __restrict__ sig, const float* __restrict__ scores,
                        const int* __restrict__ seedNode, const int* __restrict__ Scnt,
                        float* __restrict__ out) {
    int b = blockIdx.y;
    int slot = blockIdx.x * 4 + (threadIdx.x >> 6);
    int lane = threadIdx.x & 63;
    float* orow = out + ((size_t)(b * NDIM + slot)) * CDIM + lane * 4;
    if (slot < Scnt[b]) {
        int s = seedNode[b * NN + slot];
        float4 v = *(const float4*)(sig + sig_off(b, s) + lane * 4);
        *(float4*)orow = v;
        if (lane == 0) {
            out[(size_t)BDIM * NDIM * CDIM + (size_t)b * NDIM + slot] = 1.0f;
            out[(size_t)BDIM * NDIM * CDIM + (size_t)BDIM * NDIM + (size_t)b * NDIM + slot] =
                scores[b * NN + s];
        }
    } else {
        float4 z = {0.f, 0.f, 0.f, 0.f};
        *(float4*)orow = z;
        if (lane == 0) {
            out[(size_t)BDIM * NDIM * CDIM + (size_t)b * NDIM + slot] = 0.0f;
            out[(size_t)BDIM * NDIM * CDIM + (size_t)BDIM * NDIM + (size_t)b * NDIM + slot] = 0.0f;
        }
    }
}

extern "C" void kernel_launch(void* const* d_in, const int* in_sizes, int n_in,
                              void* d_out, int out_size, void* d_ws, size_t ws_size,
                              hipStream_t stream) {
    (void)in_sizes; (void)n_in; (void)out_size; (void)ws_size;
    const float* sig = (const float*)d_in[0];
    const float* logits = (const float*)d_in[1];
    float* out = (float*)d_out;
    char* ws = (char*)d_ws;

    const size_t arr = (size_t)BDIM * NN * 4;  // 86528 B per int/float array
    int* Mcnt = (int*)(ws + 0);
    int* Scnt = (int*)(ws + 64);
    unsigned long long* compKey = (unsigned long long*)(ws + 256);   // 2*arr bytes
    float* scores = (float*)(ws + 256 + 2 * arr);
    int* parent   = (int*)(ws + 256 + 3 * arr);
    int* selIdx   = (int*)(ws + 256 + 4 * arr);
    int* seedNode = (int*)(ws + 256 + 5 * arr);
    unsigned short* Xbf = (unsigned short*)(ws + 256 + 6 * arr);     // 11.1 MB

    k_prep<<<BDIM, 1024, 0, stream>>>(logits, scores, parent, selIdx, Mcnt);
    k_tobf<<<dim3((NDIM + 3) / 4, BDIM), 256, 0, stream>>>(sig, selIdx, Mcnt, Xbf);
    k_sim_mfma<<<NTRI * BDIM, 256, 0, stream>>>(Xbf, selIdx, Mcnt, parent);
    k_comp<<<BDIM, 1024, 0, stream>>>(parent, selIdx, Mcnt, scores, compKey, seedNode, Scnt);
    k_write<<<dim3(NDIM / 4, BDIM), 256, 0, stream>>>(sig, scores, seedNode, Scnt, out);
}

// Round 5
// 112.546 us; speedup vs baseline: 2.6086x; 1.0283x over previous
//
#include <hip/hip_runtime.h>
#include <cstdint>
#include <cstddef>

#define LDIM 6
#define BDIM 4
#define QDIM 900
#define CDIM 256
#define NDIM (LDIM*QDIM)   /* 5400 */
#define NN   5408          /* padded per-image stride */
#define T128 43            /* ceil(5400/128) */
#define NT128 (T128*(T128+1)/2) /* 946 lower-tri 128x128 tiles */

typedef short bf16x8 __attribute__((ext_vector_type(8)));
typedef float floatx4 __attribute__((ext_vector_type(4)));

__device__ __forceinline__ int sig_off(int b, int n) {
    int l = n / QDIM, q = n - l * QDIM;
    return ((l * BDIM + b) * QDIM + q) * CDIM;
}
__device__ __forceinline__ int logit_off(int b, int n) {
    int l = n / QDIM, q = n - l * QDIM;
    return (l * BDIM + b) * QDIM + q;
}

__device__ __forceinline__ int uf_load(const int* p, int i) {
    return __hip_atomic_load(&p[i], __ATOMIC_RELAXED, __HIP_MEMORY_SCOPE_AGENT);
}
__device__ int uf_find(int* p, int x) {
    int r = x;
    int pr = uf_load(p, r);
    while (pr != r) { r = pr; pr = uf_load(p, r); }
    return r;
}
__device__ void uf_union(int* p, int a, int b) {
    int ra = uf_find(p, a), rb = uf_find(p, b);
    while (ra != rb) {
        int hi = ra > rb ? ra : rb;
        int lo = ra ^ rb ^ hi;
        int old = atomicCAS(&p[hi], hi, lo);
        if (old == hi) return;
        ra = uf_find(p, old);
        rb = uf_find(p, lo);
    }
}

__device__ __forceinline__ unsigned short f2bf(float f) {
    unsigned int u = __float_as_uint(f);
    u += 0x7fffu + ((u >> 16) & 1u);   // round-to-nearest-even
    return (unsigned short)(u >> 16);
}

// K1: fused init + ordered compaction + argmax fallback. One 1024-thr block per image.
__global__ __launch_bounds__(1024) void k_prep(const float* __restrict__ logits,
                                               float* __restrict__ scores,
                                               int* __restrict__ parent,
                                               int* __restrict__ selIdx,
                                               int* __restrict__ Mcnt) {
    int b = blockIdx.x, t = threadIdx.x;
    int lane = t & 63, w = t >> 6;               // 16 waves
    __shared__ int wsum[16];
    __shared__ unsigned long long wkey[16];
    __shared__ int sbase;
    if (t == 0) sbase = 0;
    unsigned long long mykey = 0ULL;
    __syncthreads();
    for (int base = 0; base < NDIM; base += 1024) {
        int n = base + t;
        int f = 0;
        if (n < NDIM) {
            float x = logits[logit_off(b, n)];
            float sc = 1.0f / (1.0f + expf(-x));
            scores[b * NN + n] = sc;
            parent[b * NN + n] = n;
            f = (sc >= 0.5f) ? 1 : 0;
            unsigned long long key =
                ((unsigned long long)__float_as_uint(sc) << 32) | (unsigned int)(~n);
            if (key > mykey) mykey = key;
        }
        unsigned long long bal = __ballot(f != 0);
        int rank = __popcll(bal & ((1ull << lane) - 1ull));
        if (lane == 0) wsum[w] = __popcll(bal);
        __syncthreads();
        if (t == 0) {
            int s = sbase;
            for (int i = 0; i < 16; i++) { int v = wsum[i]; wsum[i] = s; s += v; }
            sbase = s;
        }
        __syncthreads();
        if (f) selIdx[b * NN + wsum[w] + rank] = n;
        __syncthreads();
    }
    for (int off = 32; off; off >>= 1) {
        unsigned long long o = __shfl_down(mykey, off);
        if (o > mykey) mykey = o;
    }
    if (lane == 0) wkey[w] = mykey;
    __syncthreads();
    if (t == 0) {
        if (sbase == 0) {
            unsigned long long k = 0ULL;
            for (int i = 0; i < 16; i++) if (wkey[i] > k) k = wkey[i];
            selIdx[b * NN + 0] = (int)(~(unsigned int)(k & 0xffffffffULL));
            Mcnt[b] = 1;
        } else {
            Mcnt[b] = sbase;
        }
    }
}

// K2: normalize + fp32->bf16 compaction with per-row chunk swizzle:
// 16B chunk c of row g stored at chunk slot c ^ (g & 7)
__global__ void k_tobf(const float* __restrict__ sig, const int* __restrict__ selIdx,
                       const int* __restrict__ Mcnt, unsigned short* __restrict__ Xbf) {
    int b = blockIdx.y;
    int g = (blockIdx.x * blockDim.x + threadIdx.x) >> 6;
    int lane = threadIdx.x & 63;
    if (g >= Mcnt[b]) return;
    int node = selIdx[b * NN + g];
    const float4 v = *(const float4*)(sig + sig_off(b, node) + lane * 4);
    float s = v.x * v.x + v.y * v.y + v.z * v.z + v.w * v.w;
    for (int off = 32; off; off >>= 1) s += __shfl_down(s, off);
    s = __shfl(s, 0);
    float ninv = rsqrtf(s + 1e-12f);
    ushort4 o;
    o.x = f2bf(v.x * ninv); o.y = f2bf(v.y * ninv);
    o.z = f2bf(v.z * ninv); o.w = f2bf(v.w * ninv);
    int c = lane >> 1;                       // logical 16B chunk 0..31
    int sc = c ^ (g & 7);                    // swizzled slot
    *(ushort4*)(Xbf + ((size_t)(b * NN + g)) * CDIM + sc * 8 + (lane & 1) * 4) = o;
}

// K3: MFMA pairwise sims, 128x128 tiles. B tile (128 rows, 64 KB) staged to LDS once;
// each of 4 waves computes 32 rows x 128 cols (16 MFMA per K-step vs 10 loads).
__global__ __launch_bounds__(256) void k_sim_mfma(const unsigned short* __restrict__ Xbf,
                                                  const int* __restrict__ selIdx,
                                                  const int* __restrict__ Mcnt,
                                                  int* __restrict__ parent) {
    int bx = blockIdx.x;
    int b = bx & 3;            // image -> XCD locality
    int t = bx >> 2;
    int M = Mcnt[b];
    int ti = (int)((sqrtf(8.0f * (float)t + 1.0f) - 1.0f) * 0.5f);
    while ((ti + 1) * (ti + 2) / 2 <= t) ti++;
    while (ti * (ti + 1) / 2 > t) ti--;
    int tj = t - ti * (ti + 1) / 2;
    if (ti * 128 >= M) return;

    extern __shared__ char Bs[];   // 128 rows x 512 B (swizzled layout preserved)

    int tid = threadIdx.x;
    int lane = tid & 63, wave = tid >> 6;
    int rsel = lane & 15, quad = lane >> 4;

    // stage B rows [tj*128, +128): 64 x 1KB contiguous copies, 16 per wave
    const char* xb = (const char*)Xbf + ((size_t)b * NN) * 512;
#pragma unroll
    for (int k = 0; k < 16; k++) {
        int i = wave * 16 + k;
        int row = min(tj * 128 + 2 * i, NN - 2);
        const char* src = xb + (size_t)row * 512 + lane * 16;
        __builtin_amdgcn_global_load_lds(
            (const __attribute__((address_space(1))) unsigned int*)src,
            (__attribute__((address_space(3))) unsigned int*)(Bs + i * 1024),
            16, 0, 0);
    }

    // A rows: wave's 32-row slab (2 x 16)
    int rA = ti * 128 + wave * 32;
    int gA0 = min(rA + rsel, M - 1);
    int gA1 = min(rA + 16 + rsel, M - 1);
    const char* pA0 = (const char*)Xbf + ((size_t)(b * NN + gA0)) * 512;
    const char* pA1 = (const char*)Xbf + ((size_t)(b * NN + gA1)) * 512;
    int swA0 = gA0 & 7, swA1 = gA1 & 7;
    int swB = rsel & 7;

    __syncthreads();   // drains global_load_lds

    floatx4 acc[2][8];
#pragma unroll
    for (int s = 0; s < 2; s++)
#pragma unroll
        for (int nj = 0; nj < 8; nj++) acc[s][nj] = (floatx4){0.f, 0.f, 0.f, 0.f};

#pragma unroll
    for (int ks = 0; ks < CDIM / 32; ks++) {
        int cq = ks * 4 + quad;
        bf16x8 a0 = *(const bf16x8*)(pA0 + ((cq ^ swA0) << 4));
        bf16x8 a1 = *(const bf16x8*)(pA1 + ((cq ^ swA1) << 4));
        int cb = (cq ^ swB) << 4;
#pragma unroll
        for (int nj = 0; nj < 8; nj++) {
            bf16x8 bb = *(const bf16x8*)(Bs + (nj * 16 + rsel) * 512 + cb);
            acc[0][nj] = __builtin_amdgcn_mfma_f32_16x16x32_bf16(a0, bb, acc[0][nj], 0, 0, 0);
            acc[1][nj] = __builtin_amdgcn_mfma_f32_16x16x32_bf16(a1, bb, acc[1][nj], 0, 0, 0);
        }
    }

#pragma unroll
    for (int s = 0; s < 2; s++) {
        int rowA = rA + s * 16 + quad * 4;
#pragma unroll
        for (int nj = 0; nj < 8; nj++) {
            int gj = tj * 128 + nj * 16 + rsel;
#pragma unroll
            for (int r = 0; r < 4; r++) {
                int gi = rowA + r;
                if (gi < M && gj < M && gi > gj && acc[s][nj][r] >= 0.8f) {
                    uf_union(parent + b * NN, selIdx[b * NN + gi], selIdx[b * NN + gj]);
                }
            }
        }
    }
}

// K4: fused component stats + ranking. One 1024-thr block per image.
__global__ __launch_bounds__(1024) void k_comp(int* __restrict__ parent,
                                               const int* __restrict__ selIdx,
                                               const int* __restrict__ Mcnt,
                                               const float* __restrict__ scores,
                                               unsigned long long* __restrict__ compKey,
                                               int* __restrict__ seedNode,
                                               int* __restrict__ Scnt) {
    int b = blockIdx.x, t = threadIdx.x;
    int lane = t & 63, w = t >> 6;
    __shared__ int wsum[16];
    __shared__ int sbase;

    for (int n = t; n < NN; n += 1024) compKey[b * NN + n] = 0ULL;
    if (t == 0) sbase = 0;
    __syncthreads();

    int M = Mcnt[b];
    for (int base = 0; base < M; base += 1024) {
        int g = base + t;
        if (g < M) {
            int node = selIdx[b * NN + g];
            int root = uf_find(parent + b * NN, node);
            unsigned long long key =
                ((unsigned long long)__float_as_uint(scores[b * NN + node]) << 32) |
                (unsigned int)(~node);
            atomicMax(&compKey[b * NN + root], key);
        }
    }
    __syncthreads();

    for (int base = 0; base < NDIM; base += 1024) {
        int n = base + t;
        unsigned long long key = 0ULL;
        if (n < NDIM)
            key = __hip_atomic_load(&compKey[b * NN + n], __ATOMIC_RELAXED,
                                    __HIP_MEMORY_SCOPE_AGENT);
        int f = (key != 0ULL) ? 1 : 0;
        unsigned long long bal = __ballot(f != 0);
        int rank = __popcll(bal & ((1ull << lane) - 1ull));
        if (lane == 0) wsum[w] = __popcll(bal);
        __syncthreads();
        if (t == 0) {
            int s = sbase;
            for (int i = 0; i < 16; i++) { int v = wsum[i]; wsum[i] = s; s += v; }
            sbase = s;
        }
        __syncthreads();
        if (f) seedNode[b * NN + wsum[w] + rank] = (int)(~(unsigned int)(key & 0xffffffffULL));
        __syncthreads();
    }
    if (t == 0) Scnt[b] = sbase;
}

// K5: write seed signatures / mask / scores; zero-fill empty slots. 4 rows per block.
__global__ void k_write(const float* __restrict__ sig, const float* __restrict__ scores,
                        const int* __restrict__ seedNode, const int* __restrict__ Scnt,
                        float* __restrict__ out) {
    int b = blockIdx.y;
    int slot = blockIdx.x * 4 + (threadIdx.x >> 6);
    int lane = threadIdx.x & 63;
    float* orow = out + ((size_t)(b * NDIM + slot)) * CDIM + lane * 4;
    if (slot < Scnt[b]) {
        int s = seedNode[b * NN + slot];
        float4 v = *(const float4*)(sig + sig_off(b, s) + lane * 4);
        *(float4*)orow = v;
        if (lane == 0) {
            out[(size_t)BDIM * NDIM * CDIM + (size_t)b * NDIM + slot] = 1.0f;
            out[(size_t)BDIM * NDIM * CDIM + (size_t)BDIM * NDIM + (size_t)b * NDIM + slot] =
                scores[b * NN + s];
        }
    } else {
        float4 z = {0.f, 0.f, 0.f, 0.f};
        *(float4*)orow = z;
        if (lane == 0) {
            out[(size_t)BDIM * NDIM * CDIM + (size_t)b * NDIM + slot] = 0.0f;
            out[(size_t)BDIM * NDIM * CDIM + (size_t)BDIM * NDIM + (size_t)b * NDIM + slot] = 0.0f;
        }
    }
}

extern "C" void kernel_launch(void* const* d_in, const int* in_sizes, int n_in,
                              void* d_out, int out_size, void* d_ws, size_t ws_size,
                              hipStream_t stream) {
    (void)in_sizes; (void)n_in; (void)out_size; (void)ws_size;
    const float* sig = (const float*)d_in[0];
    const float* logits = (const float*)d_in[1];
    float* out = (float*)d_out;
    char* ws = (char*)d_ws;

    const size_t arr = (size_t)BDIM * NN * 4;  // 86528 B per int/float array
    int* Mcnt = (int*)(ws + 0);
    int* Scnt = (int*)(ws + 64);
    unsigned long long* compKey = (unsigned long long*)(ws + 256);   // 2*arr bytes
    float* scores = (float*)(ws + 256 + 2 * arr);
    int* parent   = (int*)(ws + 256 + 3 * arr);
    int* selIdx   = (int*)(ws + 256 + 4 * arr);
    int* seedNode = (int*)(ws + 256 + 5 * arr);
    unsigned short* Xbf = (unsigned short*)(ws + 256 + 6 * arr);     // 11.1 MB

    k_prep<<<BDIM, 1024, 0, stream>>>(logits, scores, parent, selIdx, Mcnt);
    k_tobf<<<dim3((NDIM + 3) / 4, BDIM), 256, 0, stream>>>(sig, selIdx, Mcnt, Xbf);
    k_sim_mfma<<<NT128 * BDIM, 256, 65536, stream>>>(Xbf, selIdx, Mcnt, parent);
    k_comp<<<BDIM, 1024, 0, stream>>>(parent, selIdx, Mcnt, scores, compKey, seedNode, Scnt);
    k_write<<<dim3(NDIM / 4, BDIM), 256, 0, stream>>>(sig, scores, seedNode, Scnt, out);
}

// Round 6
// 109.683 us; speedup vs baseline: 2.6767x; 1.0261x over previous
//
#include <hip/hip_runtime.h>
#include <cstdint>
#include <cstddef>

#define LDIM 6
#define BDIM 4
#define QDIM 900
#define CDIM 256
#define NDIM (LDIM*QDIM)   /* 5400 */
#define NN   5408          /* padded per-image stride */
#define T128 43            /* ceil(5400/128) */
#define NT128 (T128*(T128+1)/2) /* 946 lower-tri 128x128 tiles */

typedef float floatx4 __attribute__((ext_vector_type(4)));

__device__ __forceinline__ int sig_off(int b, int n) {
    int l = n / QDIM, q = n - l * QDIM;
    return ((l * BDIM + b) * QDIM + q) * CDIM;
}
__device__ __forceinline__ int logit_off(int b, int n) {
    int l = n / QDIM, q = n - l * QDIM;
    return (l * BDIM + b) * QDIM + q;
}

__device__ __forceinline__ int uf_load(const int* p, int i) {
    return __hip_atomic_load(&p[i], __ATOMIC_RELAXED, __HIP_MEMORY_SCOPE_AGENT);
}
__device__ int uf_find(int* p, int x) {
    int r = x;
    int pr = uf_load(p, r);
    while (pr != r) { r = pr; pr = uf_load(p, r); }
    return r;
}
__device__ void uf_union(int* p, int a, int b) {
    int ra = uf_find(p, a), rb = uf_find(p, b);
    while (ra != rb) {
        int hi = ra > rb ? ra : rb;
        int lo = ra ^ rb ^ hi;
        int old = atomicCAS(&p[hi], hi, lo);
        if (old == hi) return;
        ra = uf_find(p, old);
        rb = uf_find(p, lo);
    }
}

__device__ __forceinline__ int pk_fp8x4(float a, float b, float c, float d) {
    int p = __builtin_amdgcn_cvt_pk_fp8_f32(a, b, 0, false);   // bytes 0,1
    p = __builtin_amdgcn_cvt_pk_fp8_f32(c, d, p, true);        // bytes 2,3
    return p;
}

// K1: wide init — scores, parent, compKey=0, UNORDERED selIdx compaction (per-wave
// atomic slot claim), per-image argmax key, last-block argmax fallback.
__global__ void k_init(const float* __restrict__ logits, float* __restrict__ scores,
                       int* __restrict__ parent, unsigned long long* __restrict__ compKey,
                       int* __restrict__ selIdx, int* __restrict__ Mcnt,
                       unsigned long long* __restrict__ argKey, int* __restrict__ done) {
    int b = blockIdx.y;
    int n = blockIdx.x * 256 + threadIdx.x;
    int lane = threadIdx.x & 63;
    if (n < NN) compKey[b * NN + n] = 0ULL;
    unsigned long long key = 0ULL;
    int f = 0;
    if (n < NDIM) {
        float x = logits[logit_off(b, n)];
        float sc = 1.0f / (1.0f + expf(-x));
        scores[b * NN + n] = sc;
        parent[b * NN + n] = n;
        f = (sc >= 0.5f) ? 1 : 0;
        key = ((unsigned long long)__float_as_uint(sc) << 32) | (unsigned int)(~n);
    }
    unsigned long long bal = __ballot(f != 0);
    int cnt = __popcll(bal);
    int rank = __popcll(bal & ((1ull << lane) - 1ull));
    int base = 0;
    if (lane == 0 && cnt) base = atomicAdd(&Mcnt[b], cnt);
    base = __shfl(base, 0);
    if (f) selIdx[b * NN + base + rank] = n;
    // wave argmax -> global
    for (int off = 32; off; off >>= 1) {
        unsigned long long o = __shfl_down(key, off);
        if (o > key) key = o;
    }
    if (lane == 0) atomicMax(&argKey[b], key);
    __syncthreads();
    if (threadIdx.x == 0) {
        int prev = __hip_atomic_fetch_add(&done[b], 1, __ATOMIC_ACQ_REL,
                                          __HIP_MEMORY_SCOPE_AGENT);
        if (prev == (int)gridDim.x - 1) {   // last block: fallback if nothing selected
            if (__hip_atomic_load(&Mcnt[b], __ATOMIC_RELAXED, __HIP_MEMORY_SCOPE_AGENT) == 0) {
                unsigned long long k = __hip_atomic_load(&argKey[b], __ATOMIC_RELAXED,
                                                         __HIP_MEMORY_SCOPE_AGENT);
                selIdx[b * NN + 0] = (int)(~(unsigned int)(k & 0xffffffffULL));
                __hip_atomic_store(&Mcnt[b], 1, __ATOMIC_RELAXED, __HIP_MEMORY_SCOPE_AGENT);
            }
        }
    }
}

// K2: normalize + fp32->fp8(e4m3) compaction. Row = 256 B = 16 chunks of 16 B;
// chunk c stored at slot c ^ (g & 15). One wave per row.
__global__ void k_tobf(const float* __restrict__ sig, const int* __restrict__ selIdx,
                       const int* __restrict__ Mcnt, char* __restrict__ Xf8) {
    int b = blockIdx.y;
    int g = (blockIdx.x * blockDim.x + threadIdx.x) >> 6;
    int lane = threadIdx.x & 63;
    if (g >= Mcnt[b]) return;
    int node = selIdx[b * NN + g];
    const float4 v = *(const float4*)(sig + sig_off(b, node) + lane * 4);
    float s = v.x * v.x + v.y * v.y + v.z * v.z + v.w * v.w;
    for (int off = 32; off; off >>= 1) s += __shfl_down(s, off);
    s = __shfl(s, 0);
    float ninv = rsqrtf(s + 1e-12f);
    int p = pk_fp8x4(v.x * ninv, v.y * ninv, v.z * ninv, v.w * ninv);
    int slot = (lane >> 2) ^ (g & 15);
    *(int*)(Xf8 + ((size_t)(b * NN + g)) * 256 + slot * 16 + (lane & 3) * 4) = p;
}

// K3: fp8 MFMA pairwise sims, 128x128 tiles. B tile (128 rows, 32 KB) staged to LDS;
// A rows direct from global. 16 MFMA per K-step per wave.
__global__ __launch_bounds__(256) void k_sim_mfma(const char* __restrict__ Xf8,
                                                  const int* __restrict__ selIdx,
                                                  const int* __restrict__ Mcnt,
                                                  int* __restrict__ parent) {
    int bx = blockIdx.x;
    int b = bx & 3;            // image -> XCD locality
    int t = bx >> 2;
    int M = Mcnt[b];
    int ti = (int)((sqrtf(8.0f * (float)t + 1.0f) - 1.0f) * 0.5f);
    while ((ti + 1) * (ti + 2) / 2 <= t) ti++;
    while (ti * (ti + 1) / 2 > t) ti--;
    int tj = t - ti * (ti + 1) / 2;
    if (ti * 128 >= M) return;

    extern __shared__ char Bs[];   // 128 rows x 256 B (swizzled layout preserved)

    int tid = threadIdx.x;
    int lane = tid & 63, wave = tid >> 6;
    int rsel = lane & 15, quad = lane >> 4;

    // stage B rows [tj*128, +128): 32 x 1KB contiguous copies (4 rows each), 8 per wave
    const char* xb = Xf8 + ((size_t)b * NN) * 256;
#pragma unroll
    for (int k = 0; k < 8; k++) {
        int i = wave * 8 + k;
        int row = min(tj * 128 + 4 * i, NN - 4);
        const char* src = xb + (size_t)row * 256 + lane * 16;
        __builtin_amdgcn_global_load_lds(
            (const __attribute__((address_space(1))) unsigned int*)src,
            (__attribute__((address_space(3))) unsigned int*)(Bs + i * 1024),
            16, 0, 0);
    }

    // A rows: wave's 32-row slab (2 x 16)
    int rA = ti * 128 + wave * 32;
    int gA0 = min(rA + rsel, M - 1);
    int gA1 = min(rA + 16 + rsel, M - 1);
    const char* pA0 = Xf8 + ((size_t)(b * NN + gA0)) * 256;
    const char* pA1 = Xf8 + ((size_t)(b * NN + gA1)) * 256;
    int swA0 = gA0 & 15, swA1 = gA1 & 15;

    __syncthreads();   // drains global_load_lds

    floatx4 acc[2][8];
#pragma unroll
    for (int s = 0; s < 2; s++)
#pragma unroll
        for (int nj = 0; nj < 8; nj++) acc[s][nj] = (floatx4){0.f, 0.f, 0.f, 0.f};

#pragma unroll
    for (int ks = 0; ks < 8; ks++) {
        int ch = ks * 2 + (quad >> 1);       // logical 16B chunk of the 32B K-slab half
        int ih = (quad & 1) * 8;             // 8B half within chunk
        long a0 = *(const long*)(pA0 + ((ch ^ swA0) << 4) + ih);
        long a1 = *(const long*)(pA1 + ((ch ^ swA1) << 4) + ih);
#pragma unroll
        for (int nj = 0; nj < 8; nj++) {
            int lr = nj * 16 + rsel;
            long bb = *(const long*)(Bs + lr * 256 + (((ch ^ (lr & 15)) << 4) + ih));
            acc[0][nj] = __builtin_amdgcn_mfma_f32_16x16x32_fp8_fp8(a0, bb, acc[0][nj], 0, 0, 0);
            acc[1][nj] = __builtin_amdgcn_mfma_f32_16x16x32_fp8_fp8(a1, bb, acc[1][nj], 0, 0, 0);
        }
    }

#pragma unroll
    for (int s = 0; s < 2; s++) {
        int rowA = rA + s * 16 + quad * 4;
#pragma unroll
        for (int nj = 0; nj < 8; nj++) {
            int gj = tj * 128 + nj * 16 + rsel;
#pragma unroll
            for (int r = 0; r < 4; r++) {
                int gi = rowA + r;
                if (gi < M && gj < M && gi > gj && acc[s][nj][r] >= 0.8f) {
                    uf_union(parent + b * NN, selIdx[b * NN + gi], selIdx[b * NN + gj]);
                }
            }
        }
    }
}

// K4: component stats + ranking. One 1024-thr block per image.
__global__ __launch_bounds__(1024) void k_comp(int* __restrict__ parent,
                                               const int* __restrict__ selIdx,
                                               const int* __restrict__ Mcnt,
                                               const float* __restrict__ scores,
                                               unsigned long long* __restrict__ compKey,
                                               int* __restrict__ seedNode,
                                               int* __restrict__ Scnt) {
    int b = blockIdx.x, t = threadIdx.x;
    int lane = t & 63, w = t >> 6;
    __shared__ int wsum[16];
    __shared__ int sbase;
    if (t == 0) sbase = 0;
    __syncthreads();

    // phase 1: per selected node, find root, max packed (score, ~idx) key
    int M = Mcnt[b];
    for (int base = 0; base < M; base += 1024) {
        int g = base + t;
        if (g < M) {
            int node = selIdx[b * NN + g];
            int root = uf_find(parent + b * NN, node);
            unsigned long long key =
                ((unsigned long long)__float_as_uint(scores[b * NN + node]) << 32) |
                (unsigned int)(~node);
            atomicMax(&compKey[b * NN + root], key);
        }
    }
    __syncthreads();

    // phase 2: rank seeded roots ascending (agent-scope loads to bypass stale L1)
    for (int base = 0; base < NDIM; base += 1024) {
        int n = base + t;
        unsigned long long key = 0ULL;
        if (n < NDIM)
            key = __hip_atomic_load(&compKey[b * NN + n], __ATOMIC_RELAXED,
                                    __HIP_MEMORY_SCOPE_AGENT);
        int f = (key != 0ULL) ? 1 : 0;
        unsigned long long bal = __ballot(f != 0);
        int rank = __popcll(bal & ((1ull << lane) - 1ull));
        if (lane == 0) wsum[w] = __popcll(bal);
        __syncthreads();
        if (t == 0) {
            int s = sbase;
            for (int i = 0; i < 16; i++) { int v = wsum[i]; wsum[i] = s; s += v; }
            sbase = s;
        }
        __syncthreads();
        if (f) seedNode[b * NN + wsum[w] + rank] = (int)(~(unsigned int)(key & 0xffffffffULL));
        __syncthreads();
    }
    if (t == 0) Scnt[b] = sbase;
}

// K5: write seed signatures / mask / scores; zero-fill empty slots. 4 rows per block.
__global__ void k_write(const float* __restrict__ sig, const float* __restrict__ scores,
                        const int* __restrict__ seedNode, const int* __restrict__ Scnt,
                        float* __restrict__ out) {
    int b = blockIdx.y;
    int slot = blockIdx.x * 4 + (threadIdx.x >> 6);
    int lane = threadIdx.x & 63;
    float* orow = out + ((size_t)(b * NDIM + slot)) * CDIM + lane * 4;
    if (slot < Scnt[b]) {
        int s = seedNode[b * NN + slot];
        float4 v = *(const float4*)(sig + sig_off(b, s) + lane * 4);
        *(float4*)orow = v;
        if (lane == 0) {
            out[(size_t)BDIM * NDIM * CDIM + (size_t)b * NDIM + slot] = 1.0f;
            out[(size_t)BDIM * NDIM * CDIM + (size_t)BDIM * NDIM + (size_t)b * NDIM + slot] =
                scores[b * NN + s];
        }
    } else {
        float4 z = {0.f, 0.f, 0.f, 0.f};
        *(float4*)orow = z;
        if (lane == 0) {
            out[(size_t)BDIM * NDIM * CDIM + (size_t)b * NDIM + slot] = 0.0f;
            out[(size_t)BDIM * NDIM * CDIM + (size_t)BDIM * NDIM + (size_t)b * NDIM + slot] = 0.0f;
        }
    }
}

extern "C" void kernel_launch(void* const* d_in, const int* in_sizes, int n_in,
                              void* d_out, int out_size, void* d_ws, size_t ws_size,
                              hipStream_t stream) {
    (void)in_sizes; (void)n_in; (void)out_size; (void)ws_size;
    const float* sig = (const float*)d_in[0];
    const float* logits = (const float*)d_in[1];
    float* out = (float*)d_out;
    char* ws = (char*)d_ws;

    const size_t arr = (size_t)BDIM * NN * 4;  // 86528 B per int/float array
    int* Mcnt = (int*)(ws + 0);                       // 16 B
    int* Scnt = (int*)(ws + 64);                      // 16 B
    unsigned long long* argKey = (unsigned long long*)(ws + 128);  // 32 B
    int* done = (int*)(ws + 192);                     // 16 B
    unsigned long long* compKey = (unsigned long long*)(ws + 256); // 2*arr
    float* scores = (float*)(ws + 256 + 2 * arr);
    int* parent   = (int*)(ws + 256 + 3 * arr);
    int* selIdx   = (int*)(ws + 256 + 4 * arr);
    int* seedNode = (int*)(ws + 256 + 5 * arr);
    char* Xf8     = (char*)(ws + 256 + 6 * arr);      // BDIM*NN*256 = 5.5 MB

    hipMemsetAsync(ws, 0, 512, stream);   // header: Mcnt/Scnt/argKey/done

    k_init<<<dim3((NN + 255) / 256, BDIM), 256, 0, stream>>>(
        logits, scores, parent, compKey, selIdx, Mcnt, argKey, done);
    k_tobf<<<dim3((NDIM + 3) / 4, BDIM), 256, 0, stream>>>(sig, selIdx, Mcnt, Xf8);
    k_sim_mfma<<<NT128 * BDIM, 256, 32768, stream>>>(Xf8, selIdx, Mcnt, parent);
    k_comp<<<BDIM, 1024, 0, stream>>>(parent, selIdx, Mcnt, scores, compKey, seedNode, Scnt);
    k_write<<<dim3(NDIM / 4, BDIM), 256, 0, stream>>>(sig, scores, seedNode, Scnt, out);
}